// Round 1
// baseline (1480.868 us; speedup 1.0000x reference)
//
#include <hip/hip_runtime.h>

#define NN 50000
#define NE 800000
#define DIN 128
#define DH 200
#define DHP 256   // padded hidden
#define DO 64

// ---------------- copy x -> h (h = x, then atomics add agg) ----------------
__global__ __launch_bounds__(256) void k_copy(const float4* __restrict__ x,
                                              float4* __restrict__ h, int n4) {
  int i = blockIdx.x * 256 + threadIdx.x;
  if (i < n4) h[i] = x[i];
}

// ---------------- SpMM via atomics: h[row[e]] += val[e] * x[col[e]] --------
__global__ __launch_bounds__(256) void k_spmm(const float* __restrict__ x,
                                              const int* __restrict__ row,
                                              const int* __restrict__ col,
                                              const float* __restrict__ val,
                                              float* __restrict__ h) {
  long long idx = (long long)blockIdx.x * 256 + threadIdx.x;  // NE*32 threads
  int e = (int)(idx >> 5);
  if (e >= NE) return;
  int d = ((int)idx & 31) << 2;  // feature offset, 4 floats per thread
  int r = row[e], c = col[e];
  float v = val[e];
  const float4 xv = *reinterpret_cast<const float4*>(x + (size_t)c * DIN + d);
  float* dst = h + (size_t)r * DIN + d;
  atomicAdd(dst + 0, v * xv.x);
  atomicAdd(dst + 1, v * xv.y);
  atomicAdd(dst + 2, v * xv.z);
  atomicAdd(dst + 3, v * xv.w);
}

// ---------------- GEMM1: H2[N,256] = relu(h[N,128] @ W1[128,200] + b1) -----
// BM=128, BN=128, BK=32, 256 threads, 8x8 per-thread tile.
__global__ __launch_bounds__(256) void k_gemm1(const float* __restrict__ A,
                                               const float* __restrict__ W1,
                                               const float* __restrict__ b1,
                                               float* __restrict__ H) {
  __shared__ float As[32][132];  // transposed A tile, +4 pad (16B-aligned rows)
  __shared__ float Bs[32][128];
  const int tid = threadIdx.x;
  const int m_base = blockIdx.x * 128;
  const int n_base = blockIdx.y * 128;
  const int tm = tid >> 4, tn = tid & 15;
  float acc[8][8] = {};

  for (int kt = 0; kt < DIN; kt += 32) {
    __syncthreads();
    // A tile: 128 rows x 32 k, coalesced float4 rows, transposed store
#pragma unroll
    for (int j = 0; j < 4; ++j) {
      int li = tid + 256 * j;
      int rr = li >> 3;  // 0..127
      int kq = li & 7;   // float4 index within 32-k strip
      int gm = m_base + rr;
      float4 av = make_float4(0.f, 0.f, 0.f, 0.f);
      if (gm < NN)
        av = *reinterpret_cast<const float4*>(A + (size_t)gm * DIN + kt + kq * 4);
      As[kq * 4 + 0][rr] = av.x;
      As[kq * 4 + 1][rr] = av.y;
      As[kq * 4 + 2][rr] = av.z;
      As[kq * 4 + 3][rr] = av.w;
    }
    // B tile: 32 k x 128 n, scalar guarded loads (zero-fill past col 200)
#pragma unroll
    for (int j = 0; j < 16; ++j) {
      int li = tid + 256 * j;
      int kk = li >> 7;   // 0..31
      int nn = li & 127;  // 0..127
      int gn = n_base + nn;
      Bs[kk][nn] = (gn < DH) ? W1[(size_t)(kt + kk) * DH + gn] : 0.f;
    }
    __syncthreads();
#pragma unroll
    for (int k = 0; k < 32; ++k) {
      float4 a0 = *reinterpret_cast<const float4*>(&As[k][tm * 4]);
      float4 a1 = *reinterpret_cast<const float4*>(&As[k][tm * 4 + 64]);
      float4 bb0 = *reinterpret_cast<const float4*>(&Bs[k][tn * 4]);
      float4 bb1 = *reinterpret_cast<const float4*>(&Bs[k][tn * 4 + 64]);
      float a[8] = {a0.x, a0.y, a0.z, a0.w, a1.x, a1.y, a1.z, a1.w};
      float b[8] = {bb0.x, bb0.y, bb0.z, bb0.w, bb1.x, bb1.y, bb1.z, bb1.w};
#pragma unroll
      for (int i = 0; i < 8; ++i)
#pragma unroll
        for (int jj = 0; jj < 8; ++jj) acc[i][jj] += a[i] * b[jj];
    }
  }
  // epilogue: bias + relu, pad cols (>=200) written as 0
#pragma unroll
  for (int i = 0; i < 8; ++i) {
    int gm = m_base + tm * 4 + (i < 4 ? i : 64 + (i - 4));
    if (gm >= NN) continue;
#pragma unroll
    for (int g = 0; g < 2; ++g) {
      int gn0 = n_base + tn * 4 + g * 64;
      float4 o;
      float* op = &o.x;
#pragma unroll
      for (int jj = 0; jj < 4; ++jj) {
        int gn = gn0 + jj;
        float res = 0.f;
        if (gn < DH) {
          res = acc[i][g * 4 + jj] + b1[gn];
          res = res > 0.f ? res : 0.f;
        }
        op[jj] = res;
      }
      *reinterpret_cast<float4*>(H + (size_t)gm * DHP + gn0) = o;
    }
  }
}

// ---------------- GEMM2: out[N,64] = H2[N,256] @ W2[200,64] + b2 -----------
// BM=128, BN=64, BK=32, 256 threads, 8x4 per-thread tile.
__global__ __launch_bounds__(256) void k_gemm2(const float* __restrict__ H,
                                               const float* __restrict__ W2,
                                               const float* __restrict__ b2,
                                               float* __restrict__ out) {
  __shared__ float As[32][132];
  __shared__ float Bs[32][64];
  const int tid = threadIdx.x;
  const int m_base = blockIdx.x * 128;
  const int tm = tid >> 4, tn = tid & 15;
  float acc[8][4] = {};

  for (int kt = 0; kt < DHP; kt += 32) {
    __syncthreads();
#pragma unroll
    for (int j = 0; j < 4; ++j) {
      int li = tid + 256 * j;
      int rr = li >> 3;
      int kq = li & 7;
      int gm = m_base + rr;
      float4 av = make_float4(0.f, 0.f, 0.f, 0.f);
      if (gm < NN)
        av = *reinterpret_cast<const float4*>(H + (size_t)gm * DHP + kt + kq * 4);
      As[kq * 4 + 0][rr] = av.x;
      As[kq * 4 + 1][rr] = av.y;
      As[kq * 4 + 2][rr] = av.z;
      As[kq * 4 + 3][rr] = av.w;
    }
    // B tile: 32 k x 64 n; zero-fill k >= 200
#pragma unroll
    for (int j = 0; j < 8; ++j) {
      int li = tid + 256 * j;
      int kk = li >> 6;  // 0..31
      int nn = li & 63;  // 0..63
      int gk = kt + kk;
      Bs[kk][nn] = (gk < DH) ? W2[(size_t)gk * DO + nn] : 0.f;
    }
    __syncthreads();
#pragma unroll
    for (int k = 0; k < 32; ++k) {
      float4 a0 = *reinterpret_cast<const float4*>(&As[k][tm * 4]);
      float4 a1 = *reinterpret_cast<const float4*>(&As[k][tm * 4 + 64]);
      float4 bb = *reinterpret_cast<const float4*>(&Bs[k][tn * 4]);
      float a[8] = {a0.x, a0.y, a0.z, a0.w, a1.x, a1.y, a1.z, a1.w};
      float b[4] = {bb.x, bb.y, bb.z, bb.w};
#pragma unroll
      for (int i = 0; i < 8; ++i)
#pragma unroll
        for (int jj = 0; jj < 4; ++jj) acc[i][jj] += a[i] * b[jj];
    }
  }
  float4 bias = *reinterpret_cast<const float4*>(&b2[tn * 4]);
  float bv[4] = {bias.x, bias.y, bias.z, bias.w};
#pragma unroll
  for (int i = 0; i < 8; ++i) {
    int gm = m_base + tm * 4 + (i < 4 ? i : 64 + (i - 4));
    if (gm >= NN) continue;
    float4 o;
    o.x = acc[i][0] + bv[0];
    o.y = acc[i][1] + bv[1];
    o.z = acc[i][2] + bv[2];
    o.w = acc[i][3] + bv[3];
    *reinterpret_cast<float4*>(out + (size_t)gm * DO + tn * 4) = o;
  }
}

extern "C" void kernel_launch(void* const* d_in, const int* in_sizes, int n_in,
                              void* d_out, int out_size, void* d_ws, size_t ws_size,
                              hipStream_t stream) {
  const float* x = (const float*)d_in[0];
  const int* erow = (const int*)d_in[1];
  const int* ecol = (const int*)d_in[2];
  const float* eval_ = (const float*)d_in[3];
  const float* W1 = (const float*)d_in[4];
  const float* b1 = (const float*)d_in[5];
  const float* W2 = (const float*)d_in[6];
  const float* b2 = (const float*)d_in[7];
  float* out = (float*)d_out;

  float* h = (float*)d_ws;                                              // [NN,128]
  float* h2 = (float*)((char*)d_ws + (size_t)NN * DIN * sizeof(float)); // [NN,256]

  int n4 = NN * DIN / 4;
  k_copy<<<(n4 + 255) / 256, 256, 0, stream>>>((const float4*)x, (float4*)h, n4);

  long long tot = (long long)NE * 32;
  k_spmm<<<(int)((tot + 255) / 256), 256, 0, stream>>>(x, erow, ecol, eval_, h);

  dim3 g1((NN + 127) / 128, 2);
  k_gemm1<<<g1, 256, 0, stream>>>(h, W1, b1, h2);

  k_gemm2<<<(NN + 127) / 128, 256, 0, stream>>>(h2, W2, b2, out);
}

// Round 2
// 336.570 us; speedup vs baseline: 4.3999x; 4.3999x over previous
//
#include <hip/hip_runtime.h>

#define NN 50000
#define NE 800000
#define DIN 128
#define DH 200
#define DHP 256   // padded hidden
#define DO 64

// ---------------- CSR build: histogram ----------------
__global__ __launch_bounds__(256) void k_hist(const int* __restrict__ row,
                                              int* __restrict__ deg) {
  int e = blockIdx.x * 256 + threadIdx.x;
  if (e < NE) atomicAdd(&deg[row[e]], 1);
}

// ---------------- CSR build: single-block exclusive scan ----------------
__global__ __launch_bounds__(1024) void k_scan(const int* __restrict__ deg,
                                               int* __restrict__ off,
                                               int* __restrict__ cur) {
  __shared__ int wsum[16];
  __shared__ int carry_s;
  const int lane = threadIdx.x & 63;
  const int wid = threadIdx.x >> 6;
  if (threadIdx.x == 0) carry_s = 0;
  __syncthreads();
  for (int base = 0; base < NN; base += 1024) {
    int i = base + threadIdx.x;
    int v = (i < NN) ? deg[i] : 0;
    // inclusive scan within wave (64 lanes)
    int incl = v;
#pragma unroll
    for (int d = 1; d < 64; d <<= 1) {
      int t = __shfl_up(incl, d, 64);
      if (lane >= d) incl += t;
    }
    if (lane == 63) wsum[wid] = incl;
    __syncthreads();
    if (wid == 0) {
      int w = (lane < 16) ? wsum[lane] : 0;
#pragma unroll
      for (int d = 1; d < 16; d <<= 1) {
        int t = __shfl_up(w, d, 64);
        if (lane >= d) w += t;
      }
      if (lane < 16) wsum[lane] = w;  // inclusive wave-sums
    }
    __syncthreads();
    int wbase = (wid > 0) ? wsum[wid - 1] : 0;
    int excl = carry_s + wbase + incl - v;
    if (i < NN) { off[i] = excl; cur[i] = excl; }
    __syncthreads();
    if (threadIdx.x == 1023) carry_s += wsum[15];
    __syncthreads();
  }
  if (threadIdx.x == 0) off[NN] = carry_s;  // == NE
}

// ---------------- CSR build: scatter edges into row-sorted order ----------
__global__ __launch_bounds__(256) void k_scatter(const int* __restrict__ row,
                                                 const int* __restrict__ col,
                                                 const float* __restrict__ val,
                                                 int* __restrict__ cur,
                                                 int* __restrict__ scol,
                                                 float* __restrict__ sval) {
  int e = blockIdx.x * 256 + threadIdx.x;
  if (e >= NE) return;
  int p = atomicAdd(&cur[row[e]], 1);
  scol[p] = col[e];
  sval[p] = val[e];
}

// ---------------- SpMM (CSR, gather): one wave per row ---------------------
// h[i] = x[i] + sum_j val[j] * x[col[j]];  lane owns 2 features (float2)
__global__ __launch_bounds__(256) void k_spmm_csr(const float* __restrict__ x,
                                                  const int* __restrict__ off,
                                                  const int* __restrict__ scol,
                                                  const float* __restrict__ sval,
                                                  float* __restrict__ h) {
  int r = blockIdx.x * 4 + (threadIdx.x >> 6);
  if (r >= NN) return;
  int lane = threadIdx.x & 63;
  int s = off[r], e = off[r + 1];
  const float2* xp = reinterpret_cast<const float2*>(x);
  float2 acc = make_float2(0.f, 0.f);
  int j = s;
  for (; j + 1 < e; j += 2) {
    int c0 = scol[j], c1 = scol[j + 1];
    float v0 = sval[j], v1 = sval[j + 1];
    float2 a0 = xp[(size_t)c0 * 64 + lane];
    float2 a1 = xp[(size_t)c1 * 64 + lane];
    acc.x += v0 * a0.x + v1 * a1.x;
    acc.y += v0 * a0.y + v1 * a1.y;
  }
  if (j < e) {
    int c0 = scol[j];
    float v0 = sval[j];
    float2 a0 = xp[(size_t)c0 * 64 + lane];
    acc.x += v0 * a0.x;
    acc.y += v0 * a0.y;
  }
  float2 xs = xp[(size_t)r * 64 + lane];
  acc.x += xs.x;
  acc.y += xs.y;
  reinterpret_cast<float2*>(h)[(size_t)r * 64 + lane] = acc;
}

// ---------------- GEMM1: H2[N,256] = relu(h[N,128] @ W1[128,200] + b1) -----
__global__ __launch_bounds__(256) void k_gemm1(const float* __restrict__ A,
                                               const float* __restrict__ W1,
                                               const float* __restrict__ b1,
                                               float* __restrict__ H) {
  __shared__ float As[32][132];
  __shared__ float Bs[32][128];
  const int tid = threadIdx.x;
  const int m_base = blockIdx.x * 128;
  const int n_base = blockIdx.y * 128;
  const int tm = tid >> 4, tn = tid & 15;
  float acc[8][8] = {};

  for (int kt = 0; kt < DIN; kt += 32) {
    __syncthreads();
#pragma unroll
    for (int j = 0; j < 4; ++j) {
      int li = tid + 256 * j;
      int rr = li >> 3;
      int kq = li & 7;
      int gm = m_base + rr;
      float4 av = make_float4(0.f, 0.f, 0.f, 0.f);
      if (gm < NN)
        av = *reinterpret_cast<const float4*>(A + (size_t)gm * DIN + kt + kq * 4);
      As[kq * 4 + 0][rr] = av.x;
      As[kq * 4 + 1][rr] = av.y;
      As[kq * 4 + 2][rr] = av.z;
      As[kq * 4 + 3][rr] = av.w;
    }
#pragma unroll
    for (int j = 0; j < 16; ++j) {
      int li = tid + 256 * j;
      int kk = li >> 7;
      int nn = li & 127;
      int gn = n_base + nn;
      Bs[kk][nn] = (gn < DH) ? W1[(size_t)(kt + kk) * DH + gn] : 0.f;
    }
    __syncthreads();
#pragma unroll
    for (int k = 0; k < 32; ++k) {
      float4 a0 = *reinterpret_cast<const float4*>(&As[k][tm * 4]);
      float4 a1 = *reinterpret_cast<const float4*>(&As[k][tm * 4 + 64]);
      float4 bb0 = *reinterpret_cast<const float4*>(&Bs[k][tn * 4]);
      float4 bb1 = *reinterpret_cast<const float4*>(&Bs[k][tn * 4 + 64]);
      float a[8] = {a0.x, a0.y, a0.z, a0.w, a1.x, a1.y, a1.z, a1.w};
      float b[8] = {bb0.x, bb0.y, bb0.z, bb0.w, bb1.x, bb1.y, bb1.z, bb1.w};
#pragma unroll
      for (int i = 0; i < 8; ++i)
#pragma unroll
        for (int jj = 0; jj < 8; ++jj) acc[i][jj] += a[i] * b[jj];
    }
  }
#pragma unroll
  for (int i = 0; i < 8; ++i) {
    int gm = m_base + tm * 4 + (i < 4 ? i : 64 + (i - 4));
    if (gm >= NN) continue;
#pragma unroll
    for (int g = 0; g < 2; ++g) {
      int gn0 = n_base + tn * 4 + g * 64;
      float4 o;
      float* op = &o.x;
#pragma unroll
      for (int jj = 0; jj < 4; ++jj) {
        int gn = gn0 + jj;
        float res = 0.f;
        if (gn < DH) {
          res = acc[i][g * 4 + jj] + b1[gn];
          res = res > 0.f ? res : 0.f;
        }
        op[jj] = res;
      }
      *reinterpret_cast<float4*>(H + (size_t)gm * DHP + gn0) = o;
    }
  }
}

// ---------------- GEMM2: out[N,64] = H2[N,256] @ W2[200,64] + b2 -----------
__global__ __launch_bounds__(256) void k_gemm2(const float* __restrict__ H,
                                               const float* __restrict__ W2,
                                               const float* __restrict__ b2,
                                               float* __restrict__ out) {
  __shared__ float As[32][132];
  __shared__ float Bs[32][64];
  const int tid = threadIdx.x;
  const int m_base = blockIdx.x * 128;
  const int tm = tid >> 4, tn = tid & 15;
  float acc[8][4] = {};

  for (int kt = 0; kt < DHP; kt += 32) {
    __syncthreads();
#pragma unroll
    for (int j = 0; j < 4; ++j) {
      int li = tid + 256 * j;
      int rr = li >> 3;
      int kq = li & 7;
      int gm = m_base + rr;
      float4 av = make_float4(0.f, 0.f, 0.f, 0.f);
      if (gm < NN)
        av = *reinterpret_cast<const float4*>(H + (size_t)gm * DHP + kt + kq * 4);
      As[kq * 4 + 0][rr] = av.x;
      As[kq * 4 + 1][rr] = av.y;
      As[kq * 4 + 2][rr] = av.z;
      As[kq * 4 + 3][rr] = av.w;
    }
#pragma unroll
    for (int j = 0; j < 8; ++j) {
      int li = tid + 256 * j;
      int kk = li >> 6;
      int nn = li & 63;
      int gk = kt + kk;
      Bs[kk][nn] = (gk < DH) ? W2[(size_t)gk * DO + nn] : 0.f;
    }
    __syncthreads();
#pragma unroll
    for (int k = 0; k < 32; ++k) {
      float4 a0 = *reinterpret_cast<const float4*>(&As[k][tm * 4]);
      float4 a1 = *reinterpret_cast<const float4*>(&As[k][tm * 4 + 64]);
      float4 bb = *reinterpret_cast<const float4*>(&Bs[k][tn * 4]);
      float a[8] = {a0.x, a0.y, a0.z, a0.w, a1.x, a1.y, a1.z, a1.w};
      float b[4] = {bb.x, bb.y, bb.z, bb.w};
#pragma unroll
      for (int i = 0; i < 8; ++i)
#pragma unroll
        for (int jj = 0; jj < 4; ++jj) acc[i][jj] += a[i] * b[jj];
    }
  }
  float4 bias = *reinterpret_cast<const float4*>(&b2[tn * 4]);
  float bv[4] = {bias.x, bias.y, bias.z, bias.w};
#pragma unroll
  for (int i = 0; i < 8; ++i) {
    int gm = m_base + tm * 4 + (i < 4 ? i : 64 + (i - 4));
    if (gm >= NN) continue;
    float4 o;
    o.x = acc[i][0] + bv[0];
    o.y = acc[i][1] + bv[1];
    o.z = acc[i][2] + bv[2];
    o.w = acc[i][3] + bv[3];
    *reinterpret_cast<float4*>(out + (size_t)gm * DO + tn * 4) = o;
  }
}

extern "C" void kernel_launch(void* const* d_in, const int* in_sizes, int n_in,
                              void* d_out, int out_size, void* d_ws, size_t ws_size,
                              hipStream_t stream) {
  const float* x = (const float*)d_in[0];
  const int* erow = (const int*)d_in[1];
  const int* ecol = (const int*)d_in[2];
  const float* eval_ = (const float*)d_in[3];
  const float* W1 = (const float*)d_in[4];
  const float* b1 = (const float*)d_in[5];
  const float* W2 = (const float*)d_in[6];
  const float* b2 = (const float*)d_in[7];
  float* out = (float*)d_out;

  char* ws = (char*)d_ws;
  float* h  = (float*)ws;                                    // [NN,128] = 25.6 MB
  char* r2 = ws + (size_t)NN * DIN * sizeof(float);          // 51.2 MB region
  float* h2 = (float*)r2;                                    // [NN,256] (after SpMM)
  // CSR scratch overlaid on h2 region (dead once SpMM completes):
  int*   off  = (int*)r2;                                    // NN+1 ints
  int*   cur  = (int*)(r2 + (256 << 10));                    // NN ints
  int*   deg  = (int*)(r2 + (512 << 10));                    // NN ints
  int*   scol = (int*)(r2 + (768 << 10));                    // NE ints
  float* sval = (float*)(r2 + (768 << 10) + (size_t)NE * 4); // NE floats

  hipMemsetAsync(deg, 0, (size_t)NN * sizeof(int), stream);
  k_hist<<<(NE + 255) / 256, 256, 0, stream>>>(erow, deg);
  k_scan<<<1, 1024, 0, stream>>>(deg, off, cur);
  k_scatter<<<(NE + 255) / 256, 256, 0, stream>>>(erow, ecol, eval_, cur, scol, sval);
  k_spmm_csr<<<(NN + 3) / 4, 256, 0, stream>>>(x, off, scol, sval, h);

  dim3 g1((NN + 127) / 128, 2);
  k_gemm1<<<g1, 256, 0, stream>>>(h, W1, b1, h2);
  k_gemm2<<<(NN + 127) / 128, 256, 0, stream>>>(h2, W2, b2, out);
}

// Round 3
// 267.584 us; speedup vs baseline: 5.5342x; 1.2578x over previous
//
#include <hip/hip_runtime.h>

#define NN 50000
#define NE 800000
#define DIN 128
#define DH 200
#define DHP 256   // padded hidden
#define DO 64

typedef float f32x4 __attribute__((ext_vector_type(4)));
typedef short bf16x8 __attribute__((ext_vector_type(8)));
typedef short s16x4 __attribute__((ext_vector_type(4)));

__device__ __forceinline__ unsigned short f2bf(float f) {
  unsigned int b = __float_as_uint(f);
  b = (b + 0x7FFFu + ((b >> 16) & 1u)) >> 16;
  return (unsigned short)b;
}
__device__ __forceinline__ float bf2f(unsigned short u) {
  return __uint_as_float((unsigned int)u << 16);
}

// ---------------- CSR build: histogram ----------------
__global__ __launch_bounds__(256) void k_hist(const int* __restrict__ row,
                                              int* __restrict__ deg) {
  int e = blockIdx.x * 256 + threadIdx.x;
  if (e < NE) atomicAdd(&deg[row[e]], 1);
}

// ---------------- CSR build: single-block exclusive scan ----------------
__global__ __launch_bounds__(1024) void k_scan(const int* __restrict__ deg,
                                               int* __restrict__ off,
                                               int* __restrict__ cur) {
  __shared__ int wsum[16];
  __shared__ int carry_s;
  const int lane = threadIdx.x & 63;
  const int wid = threadIdx.x >> 6;
  if (threadIdx.x == 0) carry_s = 0;
  __syncthreads();
  for (int base = 0; base < NN; base += 1024) {
    int i = base + threadIdx.x;
    int v = (i < NN) ? deg[i] : 0;
    int incl = v;
#pragma unroll
    for (int d = 1; d < 64; d <<= 1) {
      int t = __shfl_up(incl, d, 64);
      if (lane >= d) incl += t;
    }
    if (lane == 63) wsum[wid] = incl;
    __syncthreads();
    if (wid == 0) {
      int w = (lane < 16) ? wsum[lane] : 0;
#pragma unroll
      for (int d = 1; d < 16; d <<= 1) {
        int t = __shfl_up(w, d, 64);
        if (lane >= d) w += t;
      }
      if (lane < 16) wsum[lane] = w;
    }
    __syncthreads();
    int wbase = (wid > 0) ? wsum[wid - 1] : 0;
    int excl = carry_s + wbase + incl - v;
    if (i < NN) { off[i] = excl; cur[i] = excl; }
    __syncthreads();
    if (threadIdx.x == 1023) carry_s += wsum[15];
    __syncthreads();
  }
  if (threadIdx.x == 0) off[NN] = carry_s;
}

// ---------------- CSR build: scatter ----------
__global__ __launch_bounds__(256) void k_scatter(const int* __restrict__ row,
                                                 const int* __restrict__ col,
                                                 const float* __restrict__ val,
                                                 int* __restrict__ cur,
                                                 int* __restrict__ scol,
                                                 float* __restrict__ sval) {
  int e = blockIdx.x * 256 + threadIdx.x;
  if (e >= NE) return;
  int p = atomicAdd(&cur[row[e]], 1);
  scol[p] = col[e];
  sval[p] = val[e];
}

// ---------------- SpMM (CSR, gather): one wave per row ---------------------
__global__ __launch_bounds__(256) void k_spmm_csr(const float* __restrict__ x,
                                                  const int* __restrict__ off,
                                                  const int* __restrict__ scol,
                                                  const float* __restrict__ sval,
                                                  float* __restrict__ h) {
  int r = blockIdx.x * 4 + (threadIdx.x >> 6);
  if (r >= NN) return;
  int lane = threadIdx.x & 63;
  int s = off[r], e = off[r + 1];
  const float2* xp = reinterpret_cast<const float2*>(x);
  float2 acc = make_float2(0.f, 0.f);
  int j = s;
  for (; j + 1 < e; j += 2) {
    int c0 = scol[j], c1 = scol[j + 1];
    float v0 = sval[j], v1 = sval[j + 1];
    float2 a0 = xp[(size_t)c0 * 64 + lane];
    float2 a1 = xp[(size_t)c1 * 64 + lane];
    acc.x += v0 * a0.x + v1 * a1.x;
    acc.y += v0 * a0.y + v1 * a1.y;
  }
  if (j < e) {
    int c0 = scol[j];
    float v0 = sval[j];
    float2 a0 = xp[(size_t)c0 * 64 + lane];
    acc.x += v0 * a0.x;
    acc.y += v0 * a0.y;
  }
  float2 xs = xp[(size_t)r * 64 + lane];
  acc.x += xs.x;
  acc.y += xs.y;
  reinterpret_cast<float2*>(h)[(size_t)r * 64 + lane] = acc;
}

// ---------------- pack W1 -> MFMA fragment order (bf16, pad N to 256) ------
// frag (t in 0..15 n-tiles, s in 0..3 k-steps, lane, j): k = s*32+(j&3)+(lane>>4)*4+(j>>2)*16
__global__ __launch_bounds__(256) void k_pack1(const float* __restrict__ W1,
                                               unsigned short* __restrict__ B1p) {
  int idx = blockIdx.x * 256 + threadIdx.x;  // 4096 total
  int lane = idx & 63;
  int s = (idx >> 6) & 3;
  int t = idx >> 8;
  int n = t * 16 + (lane & 15);
  unsigned short v[8];
#pragma unroll
  for (int j = 0; j < 8; ++j) {
    int k = s * 32 + (j & 3) + ((lane >> 4) << 2) + ((j >> 2) << 4);
    float f = (n < DH) ? W1[(size_t)k * DH + n] : 0.f;
    v[j] = f2bf(f);
  }
  *reinterpret_cast<uint4*>(B1p + (size_t)idx * 8) =
      *reinterpret_cast<const uint4*>(v);
}

// ---------------- pack W2 -> fragment order (bf16, pad K to 256) -----------
__global__ __launch_bounds__(256) void k_pack2(const float* __restrict__ W2,
                                               unsigned short* __restrict__ B2p) {
  int idx = blockIdx.x * 256 + threadIdx.x;  // 2048 total
  int lane = idx & 63;
  int s = (idx >> 6) & 7;
  int t = idx >> 9;
  int n = t * 16 + (lane & 15);
  unsigned short v[8];
#pragma unroll
  for (int j = 0; j < 8; ++j) {
    int k = s * 32 + (j & 3) + ((lane >> 4) << 2) + ((j >> 2) << 4);
    float f = (k < DH) ? W2[(size_t)k * DO + n] : 0.f;
    v[j] = f2bf(f);
  }
  *reinterpret_cast<uint4*>(B2p + (size_t)idx * 8) =
      *reinterpret_cast<const uint4*>(v);
}

// ---------------- GEMM1 (MFMA): H2b[N,256] = relu(h@W1+b1), bf16 out -------
// BM=64, BN=256, 4 waves (2M x 2N); wave tile 32x128; A = fp32 h, hi/lo split.
__global__ __launch_bounds__(256) void k_mlp1(const float* __restrict__ h,
                                              const unsigned short* __restrict__ B1p,
                                              const float* __restrict__ b1,
                                              unsigned short* __restrict__ H2b) {
  const int tid = threadIdx.x;
  const int w = tid >> 6, l = tid & 63;
  const int wm = w >> 1, wn = w & 1;
  const int g = l >> 4, r16 = l & 15;
  const int m0 = blockIdx.x * 64 + wm * 32;

  f32x4 acc[2][8];
#pragma unroll
  for (int a = 0; a < 2; ++a)
#pragma unroll
    for (int b = 0; b < 8; ++b)
#pragma unroll
      for (int c = 0; c < 4; ++c) acc[a][b][c] = 0.f;

  int arow[2];
#pragma unroll
  for (int mr = 0; mr < 2; ++mr) {
    int rr = m0 + mr * 16 + r16;
    arow[mr] = rr < NN ? rr : NN - 1;
  }

  for (int s = 0; s < 4; ++s) {
    bf16x8 ah[2], al[2];
#pragma unroll
    for (int mr = 0; mr < 2; ++mr) {
      const float* p = h + (size_t)arow[mr] * DIN + s * 32 + g * 4;
      f32x4 va = *reinterpret_cast<const f32x4*>(p);
      f32x4 vb = *reinterpret_cast<const f32x4*>(p + 16);
      float fv[8] = {va[0], va[1], va[2], va[3], vb[0], vb[1], vb[2], vb[3]};
#pragma unroll
      for (int j = 0; j < 8; ++j) {
        unsigned short hi = f2bf(fv[j]);
        ah[mr][j] = (short)hi;
        al[mr][j] = (short)f2bf(fv[j] - bf2f(hi));
      }
    }
#pragma unroll
    for (int nr = 0; nr < 8; ++nr) {
      int t = wn * 8 + nr;
      bf16x8 bf = *reinterpret_cast<const bf16x8*>(B1p + (size_t)((t * 4 + s) * 64 + l) * 8);
      acc[0][nr] = __builtin_amdgcn_mfma_f32_16x16x32_bf16(ah[0], bf, acc[0][nr], 0, 0, 0);
      acc[0][nr] = __builtin_amdgcn_mfma_f32_16x16x32_bf16(al[0], bf, acc[0][nr], 0, 0, 0);
      acc[1][nr] = __builtin_amdgcn_mfma_f32_16x16x32_bf16(ah[1], bf, acc[1][nr], 0, 0, 0);
      acc[1][nr] = __builtin_amdgcn_mfma_f32_16x16x32_bf16(al[1], bf, acc[1][nr], 0, 0, 0);
    }
  }
#pragma unroll
  for (int mr = 0; mr < 2; ++mr)
#pragma unroll
    for (int nr = 0; nr < 8; ++nr) {
      int n = wn * 128 + nr * 16 + r16;
      float bias = (n < DH) ? b1[n] : 0.f;
#pragma unroll
      for (int i = 0; i < 4; ++i) {
        int row = m0 + mr * 16 + g * 4 + i;
        if (row < NN) {
          float v = acc[mr][nr][i] + bias;
          v = v > 0.f ? v : 0.f;
          H2b[(size_t)row * DHP + n] = f2bf(v);
        }
      }
    }
}

// ---------------- GEMM2 (MFMA): out[N,64] = H2b@W2 + b2 --------------------
// BM=64, 4 waves stacked in M; wave tile 16x64; A = bf16 H2b.
__global__ __launch_bounds__(256) void k_mlp2(const unsigned short* __restrict__ H2b,
                                              const unsigned short* __restrict__ B2p,
                                              const float* __restrict__ b2,
                                              float* __restrict__ out) {
  const int tid = threadIdx.x;
  const int w = tid >> 6, l = tid & 63;
  const int g = l >> 4, r16 = l & 15;
  const int m0 = blockIdx.x * 64 + w * 16;

  f32x4 acc[4];
#pragma unroll
  for (int b = 0; b < 4; ++b)
#pragma unroll
    for (int c = 0; c < 4; ++c) acc[b][c] = 0.f;

  int rr = m0 + r16;
  int arow = rr < NN ? rr : NN - 1;

  for (int s = 0; s < 8; ++s) {
    const unsigned short* p = H2b + (size_t)arow * DHP + s * 32 + g * 4;
    s16x4 lo4 = *reinterpret_cast<const s16x4*>(p);
    s16x4 hi4 = *reinterpret_cast<const s16x4*>(p + 16);
    bf16x8 af;
#pragma unroll
    for (int j = 0; j < 4; ++j) { af[j] = lo4[j]; af[4 + j] = hi4[j]; }
#pragma unroll
    for (int nr = 0; nr < 4; ++nr) {
      bf16x8 bf = *reinterpret_cast<const bf16x8*>(B2p + (size_t)((nr * 8 + s) * 64 + l) * 8);
      acc[nr] = __builtin_amdgcn_mfma_f32_16x16x32_bf16(af, bf, acc[nr], 0, 0, 0);
    }
  }
#pragma unroll
  for (int nr = 0; nr < 4; ++nr) {
    int n = nr * 16 + r16;
    float bias = b2[n];
#pragma unroll
    for (int i = 0; i < 4; ++i) {
      int row = m0 + g * 4 + i;
      if (row < NN) out[(size_t)row * DO + n] = acc[nr][i] + bias;
    }
  }
}

extern "C" void kernel_launch(void* const* d_in, const int* in_sizes, int n_in,
                              void* d_out, int out_size, void* d_ws, size_t ws_size,
                              hipStream_t stream) {
  const float* x = (const float*)d_in[0];
  const int* erow = (const int*)d_in[1];
  const int* ecol = (const int*)d_in[2];
  const float* eval_ = (const float*)d_in[3];
  const float* W1 = (const float*)d_in[4];
  const float* b1 = (const float*)d_in[5];
  const float* W2 = (const float*)d_in[6];
  const float* b2 = (const float*)d_in[7];
  float* out = (float*)d_out;

  char* ws = (char*)d_ws;
  float* h = (float*)ws;                                  // [NN,128] fp32 = 25.6 MB
  size_t o = (size_t)NN * DIN * sizeof(float);
  unsigned short* H2b = (unsigned short*)(ws + o);        // [NN,256] bf16 = 25.6 MB
  o += (size_t)NN * DHP * sizeof(unsigned short);
  unsigned short* B1p = (unsigned short*)(ws + o);        // 32768 bf16 = 64 KB
  o += 32768 * 2;
  unsigned short* B2p = (unsigned short*)(ws + o);        // 16384 bf16 = 32 KB
  o += 16384 * 2;
  o = (o + 255) & ~(size_t)255;
  int* off = (int*)(ws + o);                              // NN+1
  int* cur = (int*)(ws + o + (256 << 10));                // NN
  int* deg = (int*)(ws + o + (512 << 10));                // NN
  int* scol = (int*)(ws + o + (768 << 10));               // NE
  float* sval = (float*)(ws + o + (768 << 10) + (size_t)NE * 4);  // NE

  hipMemsetAsync(deg, 0, (size_t)NN * sizeof(int), stream);
  k_hist<<<(NE + 255) / 256, 256, 0, stream>>>(erow, deg);
  k_scan<<<1, 1024, 0, stream>>>(deg, off, cur);
  k_scatter<<<(NE + 255) / 256, 256, 0, stream>>>(erow, ecol, eval_, cur, scol, sval);
  k_pack1<<<16, 256, 0, stream>>>(W1, B1p);
  k_pack2<<<8, 256, 0, stream>>>(W2, B2p);
  k_spmm_csr<<<(NN + 3) / 4, 256, 0, stream>>>(x, off, scol, sval, h);

  k_mlp1<<<(NN + 63) / 64, 256, 0, stream>>>(h, B1p, b1, H2b);
  k_mlp2<<<(NN + 63) / 64, 256, 0, stream>>>(H2b, B2p, b2, out);
}

// Round 4
// 224.637 us; speedup vs baseline: 6.5923x; 1.1912x over previous
//
#include <hip/hip_runtime.h>

#define NN 50000
#define NE 800000
#define DIN 128
#define DH 200
#define DHP 256   // padded hidden
#define DO 64

typedef float f32x4 __attribute__((ext_vector_type(4)));
typedef short bf16x8 __attribute__((ext_vector_type(8)));
typedef short s16x4 __attribute__((ext_vector_type(4)));
typedef unsigned int uint;

__device__ __forceinline__ unsigned short f2bf(float f) {
  unsigned int b = __float_as_uint(f);
  b = (b + 0x7FFFu + ((b >> 16) & 1u)) >> 16;
  return (unsigned short)b;
}
__device__ __forceinline__ float bf2f(unsigned short u) {
  return __uint_as_float((unsigned int)u << 16);
}

// ---------------- x (fp32) -> xb (bf16), 8 floats/thread -------------------
__global__ __launch_bounds__(256) void k_cvt(const float* __restrict__ x,
                                             uint* __restrict__ xb) {
  int i = blockIdx.x * 256 + threadIdx.x;  // 800000 threads
  f32x4 a = *reinterpret_cast<const f32x4*>(x + (size_t)i * 8);
  f32x4 b = *reinterpret_cast<const f32x4*>(x + (size_t)i * 8 + 4);
  uint4 o;
  o.x = (uint)f2bf(a[0]) | ((uint)f2bf(a[1]) << 16);
  o.y = (uint)f2bf(a[2]) | ((uint)f2bf(a[3]) << 16);
  o.z = (uint)f2bf(b[0]) | ((uint)f2bf(b[1]) << 16);
  o.w = (uint)f2bf(b[2]) | ((uint)f2bf(b[3]) << 16);
  *reinterpret_cast<uint4*>(xb + (size_t)i * 4) = o;
}

// ---------------- CSR build: histogram ----------------
__global__ __launch_bounds__(256) void k_hist(const int* __restrict__ row,
                                              int* __restrict__ deg) {
  int e = blockIdx.x * 256 + threadIdx.x;
  if (e < NE) atomicAdd(&deg[row[e]], 1);
}

// ---------------- CSR build: single-block exclusive scan ----------------
__global__ __launch_bounds__(1024) void k_scan(const int* __restrict__ deg,
                                               int* __restrict__ off,
                                               int* __restrict__ cur) {
  __shared__ int wsum[16];
  __shared__ int carry_s;
  const int lane = threadIdx.x & 63;
  const int wid = threadIdx.x >> 6;
  if (threadIdx.x == 0) carry_s = 0;
  __syncthreads();
  for (int base = 0; base < NN; base += 1024) {
    int i = base + threadIdx.x;
    int v = (i < NN) ? deg[i] : 0;
    int incl = v;
#pragma unroll
    for (int d = 1; d < 64; d <<= 1) {
      int t = __shfl_up(incl, d, 64);
      if (lane >= d) incl += t;
    }
    if (lane == 63) wsum[wid] = incl;
    __syncthreads();
    if (wid == 0) {
      int w = (lane < 16) ? wsum[lane] : 0;
#pragma unroll
      for (int d = 1; d < 16; d <<= 1) {
        int t = __shfl_up(w, d, 64);
        if (lane >= d) w += t;
      }
      if (lane < 16) wsum[lane] = w;
    }
    __syncthreads();
    int wbase = (wid > 0) ? wsum[wid - 1] : 0;
    int excl = carry_s + wbase + incl - v;
    if (i < NN) { off[i] = excl; cur[i] = excl; }
    __syncthreads();
    if (threadIdx.x == 1023) carry_s += wsum[15];
    __syncthreads();
  }
  if (threadIdx.x == 0) off[NN] = carry_s;
}

// ---------------- CSR build: scatter (packed col+val) ----------
__global__ __launch_bounds__(256) void k_scatter(const int* __restrict__ row,
                                                 const int* __restrict__ col,
                                                 const float* __restrict__ val,
                                                 int* __restrict__ cur,
                                                 int2* __restrict__ ep) {
  int e = blockIdx.x * 256 + threadIdx.x;
  if (e >= NE) return;
  int p = atomicAdd(&cur[row[e]], 1);
  ep[p] = make_int2(col[e], __float_as_int(val[e]));
}

// ---------------- SpMM (CSR, bf16 gather): one wave per row ----------------
// h[i] = x[i] + sum_j val[j]*x[col[j]]; lane owns 2 bf16 features (one uint)
__global__ __launch_bounds__(256) void k_spmm_csr(const uint* __restrict__ xbu,
                                                  const int* __restrict__ off,
                                                  const int2* __restrict__ ep,
                                                  uint* __restrict__ hu) {
  int r = blockIdx.x * 4 + (threadIdx.x >> 6);
  if (r >= NN) return;
  int lane = threadIdx.x & 63;
  int s = off[r], e = off[r + 1];
  float ax = 0.f, ay = 0.f;
  int j = s;
  for (; j + 3 < e; j += 4) {
    int2 e0 = ep[j], e1 = ep[j + 1], e2 = ep[j + 2], e3 = ep[j + 3];
    uint a0 = xbu[(size_t)e0.x * 64 + lane];
    uint a1 = xbu[(size_t)e1.x * 64 + lane];
    uint a2 = xbu[(size_t)e2.x * 64 + lane];
    uint a3 = xbu[(size_t)e3.x * 64 + lane];
    float v0 = __int_as_float(e0.y), v1 = __int_as_float(e1.y);
    float v2 = __int_as_float(e2.y), v3 = __int_as_float(e3.y);
    ax += v0 * bf2f((unsigned short)a0) + v1 * bf2f((unsigned short)a1) +
          v2 * bf2f((unsigned short)a2) + v3 * bf2f((unsigned short)a3);
    ay += v0 * bf2f((unsigned short)(a0 >> 16)) + v1 * bf2f((unsigned short)(a1 >> 16)) +
          v2 * bf2f((unsigned short)(a2 >> 16)) + v3 * bf2f((unsigned short)(a3 >> 16));
  }
  for (; j < e; ++j) {
    int2 e0 = ep[j];
    uint a0 = xbu[(size_t)e0.x * 64 + lane];
    float v0 = __int_as_float(e0.y);
    ax += v0 * bf2f((unsigned short)a0);
    ay += v0 * bf2f((unsigned short)(a0 >> 16));
  }
  uint xs = xbu[(size_t)r * 64 + lane];
  ax += bf2f((unsigned short)xs);
  ay += bf2f((unsigned short)(xs >> 16));
  hu[(size_t)r * 64 + lane] = (uint)f2bf(ax) | ((uint)f2bf(ay) << 16);
}

// ---------------- pack W1 -> MFMA B-fragment order (bf16, pad N to 256) ----
// frag (t n-tile, s k-step, lane, j): n=t*16+(l&15), k=s*32+(j&3)+((l>>4)<<2)+((j>>2)<<4)
__global__ __launch_bounds__(256) void k_pack1(const float* __restrict__ W1,
                                               unsigned short* __restrict__ B1p) {
  int idx = blockIdx.x * 256 + threadIdx.x;  // 4096 total
  int lane = idx & 63;
  int s = (idx >> 6) & 3;
  int t = idx >> 8;
  int n = t * 16 + (lane & 15);
  unsigned short v[8];
#pragma unroll
  for (int j = 0; j < 8; ++j) {
    int k = s * 32 + (j & 3) + ((lane >> 4) << 2) + ((j >> 2) << 4);
    float f = (n < DH) ? W1[(size_t)k * DH + n] : 0.f;
    v[j] = f2bf(f);
  }
  *reinterpret_cast<uint4*>(B1p + (size_t)idx * 8) =
      *reinterpret_cast<const uint4*>(v);
}

// ---------------- pack W2 -> B-fragment order (bf16, pad K to 256) ---------
__global__ __launch_bounds__(256) void k_pack2(const float* __restrict__ W2,
                                               unsigned short* __restrict__ B2p) {
  int idx = blockIdx.x * 256 + threadIdx.x;  // 2048 total
  int lane = idx & 63;
  int s = (idx >> 6) & 7;
  int t = idx >> 9;
  int n = t * 16 + (lane & 15);
  unsigned short v[8];
#pragma unroll
  for (int j = 0; j < 8; ++j) {
    int k = s * 32 + (j & 3) + ((lane >> 4) << 2) + ((j >> 2) << 4);
    float f = (k < DH) ? W2[(size_t)k * DO + n] : 0.f;
    v[j] = f2bf(f);
  }
  *reinterpret_cast<uint4*>(B2p + (size_t)idx * 8) =
      *reinterpret_cast<const uint4*>(v);
}

// ---------------- fused MLP: out = (relu(h@W1+b1)) @ W2 + b2 ---------------
// Block = 64 rows. Stage 1: 4 waves (2M x 2N), wave tile 32x128, H2 -> LDS.
// Stage 2: wave w handles rows w*16..w*16+15, K=256 from LDS, N=64.
__global__ __launch_bounds__(256) void k_mlp(const unsigned short* __restrict__ h,
                                             const unsigned short* __restrict__ B1p,
                                             const float* __restrict__ b1,
                                             const unsigned short* __restrict__ B2p,
                                             const float* __restrict__ b2,
                                             float* __restrict__ out) {
  __shared__ unsigned short hs[64][DHP + 8];  // +8 bf16 pad: stride 528 B
  const int tid = threadIdx.x;
  const int w = tid >> 6, l = tid & 63;
  const int wm = w >> 1, wn = w & 1;
  const int g = l >> 4, r16 = l & 15;
  const int m0 = blockIdx.x * 64 + wm * 32;

  f32x4 acc[2][8];
#pragma unroll
  for (int a = 0; a < 2; ++a)
#pragma unroll
    for (int b = 0; b < 8; ++b)
#pragma unroll
      for (int c = 0; c < 4; ++c) acc[a][b][c] = 0.f;

  int arow[2];
#pragma unroll
  for (int mr = 0; mr < 2; ++mr) {
    int rr = m0 + mr * 16 + r16;
    arow[mr] = rr < NN ? rr : NN - 1;
  }

  for (int s = 0; s < 4; ++s) {
    bf16x8 af[2];
#pragma unroll
    for (int mr = 0; mr < 2; ++mr) {
      const unsigned short* p = h + (size_t)arow[mr] * DIN + s * 32 + g * 4;
      s16x4 lo4 = *reinterpret_cast<const s16x4*>(p);
      s16x4 hi4 = *reinterpret_cast<const s16x4*>(p + 16);
#pragma unroll
      for (int j = 0; j < 4; ++j) { af[mr][j] = lo4[j]; af[mr][4 + j] = hi4[j]; }
    }
#pragma unroll
    for (int nr = 0; nr < 8; ++nr) {
      int t = wn * 8 + nr;
      bf16x8 bf = *reinterpret_cast<const bf16x8*>(B1p + (size_t)((t * 4 + s) * 64 + l) * 8);
      acc[0][nr] = __builtin_amdgcn_mfma_f32_16x16x32_bf16(af[0], bf, acc[0][nr], 0, 0, 0);
      acc[1][nr] = __builtin_amdgcn_mfma_f32_16x16x32_bf16(af[1], bf, acc[1][nr], 0, 0, 0);
    }
  }
  // bias + relu -> LDS (bf16)
#pragma unroll
  for (int mr = 0; mr < 2; ++mr)
#pragma unroll
    for (int nr = 0; nr < 8; ++nr) {
      int n = wn * 128 + nr * 16 + r16;
      float bias = (n < DH) ? b1[n] : 0.f;
#pragma unroll
      for (int i = 0; i < 4; ++i) {
        int rl = wm * 32 + mr * 16 + g * 4 + i;
        float v = acc[mr][nr][i] + bias;
        v = v > 0.f ? v : 0.f;
        if (n >= DH) v = 0.f;
        hs[rl][n] = f2bf(v);
      }
    }
  __syncthreads();

  // stage 2: rows w*16 .. w*16+15
  f32x4 acc2[4];
#pragma unroll
  for (int b = 0; b < 4; ++b)
#pragma unroll
    for (int c = 0; c < 4; ++c) acc2[b][c] = 0.f;

  for (int s = 0; s < 8; ++s) {
    const unsigned short* p = &hs[w * 16 + r16][s * 32 + g * 4];
    s16x4 lo4 = *reinterpret_cast<const s16x4*>(p);
    s16x4 hi4 = *reinterpret_cast<const s16x4*>(p + 16);
    bf16x8 af;
#pragma unroll
    for (int j = 0; j < 4; ++j) { af[j] = lo4[j]; af[4 + j] = hi4[j]; }
#pragma unroll
    for (int nr = 0; nr < 4; ++nr) {
      bf16x8 bf = *reinterpret_cast<const bf16x8*>(B2p + (size_t)((nr * 8 + s) * 64 + l) * 8);
      acc2[nr] = __builtin_amdgcn_mfma_f32_16x16x32_bf16(af, bf, acc2[nr], 0, 0, 0);
    }
  }
#pragma unroll
  for (int nr = 0; nr < 4; ++nr) {
    int n = nr * 16 + r16;
    float bias = b2[n];
#pragma unroll
    for (int i = 0; i < 4; ++i) {
      int grow = blockIdx.x * 64 + w * 16 + g * 4 + i;
      if (grow < NN) out[(size_t)grow * DO + n] = acc2[nr][i] + bias;
    }
  }
}

extern "C" void kernel_launch(void* const* d_in, const int* in_sizes, int n_in,
                              void* d_out, int out_size, void* d_ws, size_t ws_size,
                              hipStream_t stream) {
  const float* x = (const float*)d_in[0];
  const int* erow = (const int*)d_in[1];
  const int* ecol = (const int*)d_in[2];
  const float* eval_ = (const float*)d_in[3];
  const float* W1 = (const float*)d_in[4];
  const float* b1 = (const float*)d_in[5];
  const float* W2 = (const float*)d_in[6];
  const float* b2 = (const float*)d_in[7];
  float* out = (float*)d_out;

  char* ws = (char*)d_ws;
  size_t o = 0;
  uint* xb = (uint*)(ws + o);          o += (size_t)NN * 64 * 4;   // x bf16, 12.8 MB
  uint* hu = (uint*)(ws + o);          o += (size_t)NN * 64 * 4;   // h bf16, 12.8 MB
  unsigned short* B1p = (unsigned short*)(ws + o); o += 32768 * 2; // 64 KB
  unsigned short* B2p = (unsigned short*)(ws + o); o += 16384 * 2; // 32 KB
  o = (o + 255) & ~(size_t)255;
  int* off = (int*)(ws + o);           o += (256 << 10);
  int* cur = (int*)(ws + o);           o += (256 << 10);
  int* deg = (int*)(ws + o);           o += (256 << 10);
  int2* ep = (int2*)(ws + o);          // NE * 8 B = 6.4 MB

  hipMemsetAsync(deg, 0, (size_t)NN * sizeof(int), stream);
  k_cvt<<<3125, 256, 0, stream>>>(x, xb);
  k_hist<<<(NE + 255) / 256, 256, 0, stream>>>(erow, deg);
  k_scan<<<1, 1024, 0, stream>>>(deg, off, cur);
  k_scatter<<<(NE + 255) / 256, 256, 0, stream>>>(erow, ecol, eval_, cur, ep);
  k_pack1<<<16, 256, 0, stream>>>(W1, B1p);
  k_pack2<<<8, 256, 0, stream>>>(W2, B2p);
  k_spmm_csr<<<(NN + 3) / 4, 256, 0, stream>>>(xb, off, ep, hu);
  k_mlp<<<(NN + 63) / 64, 256, 0, stream>>>((const unsigned short*)hu, B1p, b1,
                                            B2p, b2, out);
}

// Round 5
// 167.464 us; speedup vs baseline: 8.8429x; 1.3414x over previous
//
#include <hip/hip_runtime.h>

#define NN 50000
#define NE 800000
#define DIN 128
#define DH 200
#define DHP 256   // padded hidden
#define DO 64

typedef float f32x4 __attribute__((ext_vector_type(4)));
typedef short bf16x8 __attribute__((ext_vector_type(8)));
typedef short s16x4 __attribute__((ext_vector_type(4)));
typedef unsigned int uint;

__device__ __forceinline__ unsigned short f2bf(float f) {
  unsigned int b = __float_as_uint(f);
  b = (b + 0x7FFFu + ((b >> 16) & 1u)) >> 16;
  return (unsigned short)b;
}
__device__ __forceinline__ float bf2f(unsigned short u) {
  return __uint_as_float((unsigned int)u << 16);
}

// ---------------- x (fp32) -> xb (bf16), 8 floats/thread; also zero deg ----
__global__ __launch_bounds__(256) void k_cvt(const float* __restrict__ x,
                                             uint* __restrict__ xb,
                                             int* __restrict__ deg) {
  int i = blockIdx.x * 256 + threadIdx.x;  // 800000 threads
  if (i < NN) deg[i] = 0;
  f32x4 a = *reinterpret_cast<const f32x4*>(x + (size_t)i * 8);
  f32x4 b = *reinterpret_cast<const f32x4*>(x + (size_t)i * 8 + 4);
  uint4 o;
  o.x = (uint)f2bf(a[0]) | ((uint)f2bf(a[1]) << 16);
  o.y = (uint)f2bf(a[2]) | ((uint)f2bf(a[3]) << 16);
  o.z = (uint)f2bf(b[0]) | ((uint)f2bf(b[1]) << 16);
  o.w = (uint)f2bf(b[2]) | ((uint)f2bf(b[3]) << 16);
  *reinterpret_cast<uint4*>(xb + (size_t)i * 4) = o;
}

// ---------------- CSR build: histogram, 4 edges/thread ---------------------
__global__ __launch_bounds__(256) void k_hist(const int* __restrict__ row,
                                              int* __restrict__ deg) {
  int base = blockIdx.x * 1024 + threadIdx.x * 4;
  if (base + 3 < NE) {
    int4 r4 = *reinterpret_cast<const int4*>(row + base);
    atomicAdd(&deg[r4.x], 1);
    atomicAdd(&deg[r4.y], 1);
    atomicAdd(&deg[r4.z], 1);
    atomicAdd(&deg[r4.w], 1);
  } else {
#pragma unroll
    for (int k = 0; k < 4; ++k) {
      int e = base + k;
      if (e < NE) atomicAdd(&deg[row[e]], 1);
    }
  }
}

// ---------------- block-wide exclusive scan helper -------------------------
__device__ __forceinline__ int block_excl_scan(int v, int tid, int* wsum) {
  int lane = tid & 63, wid = tid >> 6;
  int incl = v;
#pragma unroll
  for (int d = 1; d < 64; d <<= 1) {
    int t = __shfl_up(incl, d, 64);
    if (lane >= d) incl += t;
  }
  if (lane == 63) wsum[wid] = incl;
  __syncthreads();
  if (tid == 0) {
    int s = 0;
#pragma unroll
    for (int k = 0; k < 4; ++k) { int xx = wsum[k]; wsum[k] = s; s += xx; }
  }
  __syncthreads();
  return wsum[wid] + incl - v;
}

// ---------------- scan phase A: per-block reduce ---------------------------
__global__ __launch_bounds__(256) void k_scanA(const int* __restrict__ deg,
                                               int* __restrict__ bsum) {
  __shared__ int ws[4];
  int tid = threadIdx.x;
  int i = blockIdx.x * 256 + tid;
  int v = (i < NN) ? deg[i] : 0;
#pragma unroll
  for (int d = 32; d > 0; d >>= 1) v += __shfl_down(v, d, 64);
  if ((tid & 63) == 0) ws[tid >> 6] = v;
  __syncthreads();
  if (tid == 0) bsum[blockIdx.x] = ws[0] + ws[1] + ws[2] + ws[3];
}

// ---------------- scan phase B: scan 196 block sums ------------------------
__global__ __launch_bounds__(256) void k_scanB(const int* __restrict__ bsum,
                                               int* __restrict__ bbase,
                                               int* __restrict__ off, int nb) {
  __shared__ int ws[4];
  int t = threadIdx.x;
  int v = (t < nb) ? bsum[t] : 0;
  int excl = block_excl_scan(v, t, ws);
  if (t < nb) bbase[t] = excl;
  if (t == 0) off[NN] = NE;
}

// ---------------- scan phase C: per-block scan + base ----------------------
__global__ __launch_bounds__(256) void k_scanC(const int* __restrict__ deg,
                                               const int* __restrict__ bbase,
                                               int* __restrict__ off,
                                               int* __restrict__ cur) {
  __shared__ int ws[4];
  int tid = threadIdx.x;
  int i = blockIdx.x * 256 + tid;
  int v = (i < NN) ? deg[i] : 0;
  int excl = block_excl_scan(v, tid, ws) + bbase[blockIdx.x];
  if (i < NN) { off[i] = excl; cur[i] = excl; }
}

// ---------------- CSR build: scatter (4B packed edge, 4/thread) ------------
__global__ __launch_bounds__(256) void k_scatter(const int* __restrict__ row,
                                                 const int* __restrict__ col,
                                                 const float* __restrict__ val,
                                                 int* __restrict__ cur,
                                                 uint* __restrict__ ep) {
  int base = blockIdx.x * 1024 + threadIdx.x * 4;
  if (base + 3 < NE) {
    int4 r4 = *reinterpret_cast<const int4*>(row + base);
    int4 c4 = *reinterpret_cast<const int4*>(col + base);
    float4 v4 = *reinterpret_cast<const float4*>(val + base);
    int p0 = atomicAdd(&cur[r4.x], 1);
    int p1 = atomicAdd(&cur[r4.y], 1);
    int p2 = atomicAdd(&cur[r4.z], 1);
    int p3 = atomicAdd(&cur[r4.w], 1);
    ep[p0] = (uint)c4.x | ((uint)f2bf(v4.x) << 16);
    ep[p1] = (uint)c4.y | ((uint)f2bf(v4.y) << 16);
    ep[p2] = (uint)c4.z | ((uint)f2bf(v4.z) << 16);
    ep[p3] = (uint)c4.w | ((uint)f2bf(v4.w) << 16);
  } else {
#pragma unroll
    for (int k = 0; k < 4; ++k) {
      int e = base + k;
      if (e < NE) {
        int p = atomicAdd(&cur[row[e]], 1);
        ep[p] = (uint)col[e] | ((uint)f2bf(val[e]) << 16);
      }
    }
  }
}

// ---------------- SpMM (CSR, bf16 gather): one wave per row ----------------
// h[i] = x[i] + sum_j val[j]*x[col[j]]; lane owns 2 bf16 features (one uint)
__global__ __launch_bounds__(256) void k_spmm_csr(const uint* __restrict__ xbu,
                                                  const int* __restrict__ off,
                                                  const uint* __restrict__ ep,
                                                  uint* __restrict__ hu) {
  int r = blockIdx.x * 4 + (threadIdx.x >> 6);
  if (r >= NN) return;
  int lane = threadIdx.x & 63;
  int s = off[r], e = off[r + 1];
  float ax = 0.f, ay = 0.f;
  int j = s;
  for (; j + 3 < e; j += 4) {
    uint e0 = ep[j], e1 = ep[j + 1], e2 = ep[j + 2], e3 = ep[j + 3];
    uint a0 = xbu[(size_t)(e0 & 0xFFFFu) * 64 + lane];
    uint a1 = xbu[(size_t)(e1 & 0xFFFFu) * 64 + lane];
    uint a2 = xbu[(size_t)(e2 & 0xFFFFu) * 64 + lane];
    uint a3 = xbu[(size_t)(e3 & 0xFFFFu) * 64 + lane];
    float v0 = bf2f((unsigned short)(e0 >> 16)), v1 = bf2f((unsigned short)(e1 >> 16));
    float v2 = bf2f((unsigned short)(e2 >> 16)), v3 = bf2f((unsigned short)(e3 >> 16));
    ax += v0 * bf2f((unsigned short)a0) + v1 * bf2f((unsigned short)a1) +
          v2 * bf2f((unsigned short)a2) + v3 * bf2f((unsigned short)a3);
    ay += v0 * bf2f((unsigned short)(a0 >> 16)) + v1 * bf2f((unsigned short)(a1 >> 16)) +
          v2 * bf2f((unsigned short)(a2 >> 16)) + v3 * bf2f((unsigned short)(a3 >> 16));
  }
  for (; j < e; ++j) {
    uint e0 = ep[j];
    uint a0 = xbu[(size_t)(e0 & 0xFFFFu) * 64 + lane];
    float v0 = bf2f((unsigned short)(e0 >> 16));
    ax += v0 * bf2f((unsigned short)a0);
    ay += v0 * bf2f((unsigned short)(a0 >> 16));
  }
  uint xs = xbu[(size_t)r * 64 + lane];
  ax += bf2f((unsigned short)xs);
  ay += bf2f((unsigned short)(xs >> 16));
  hu[(size_t)r * 64 + lane] = (uint)f2bf(ax) | ((uint)f2bf(ay) << 16);
}

// ---------------- pack W1+W2 -> MFMA B-fragment order ----------------------
// frag (t n-tile, s k-step, lane, j): n=t*16+(l&15), k=s*32+(j&3)+((l>>4)<<2)+((j>>2)<<4)
__global__ __launch_bounds__(256) void k_pack(const float* __restrict__ W1,
                                              const float* __restrict__ W2,
                                              unsigned short* __restrict__ B1p,
                                              unsigned short* __restrict__ B2p) {
  int gidx = blockIdx.x * 256 + threadIdx.x;  // 6144 total
  if (gidx < 4096) {
    int idx = gidx;
    int lane = idx & 63;
    int s = (idx >> 6) & 3;
    int t = idx >> 8;
    int n = t * 16 + (lane & 15);
    unsigned short v[8];
#pragma unroll
    for (int j = 0; j < 8; ++j) {
      int k = s * 32 + (j & 3) + ((lane >> 4) << 2) + ((j >> 2) << 4);
      float f = (n < DH) ? W1[(size_t)k * DH + n] : 0.f;
      v[j] = f2bf(f);
    }
    *reinterpret_cast<uint4*>(B1p + (size_t)idx * 8) =
        *reinterpret_cast<const uint4*>(v);
  } else {
    int idx = gidx - 4096;
    int lane = idx & 63;
    int s = (idx >> 6) & 7;
    int t = idx >> 9;
    int n = t * 16 + (lane & 15);
    unsigned short v[8];
#pragma unroll
    for (int j = 0; j < 8; ++j) {
      int k = s * 32 + (j & 3) + ((lane >> 4) << 2) + ((j >> 2) << 4);
      float f = (k < DH) ? W2[(size_t)k * DO + n] : 0.f;
      v[j] = f2bf(f);
    }
    *reinterpret_cast<uint4*>(B2p + (size_t)idx * 8) =
        *reinterpret_cast<const uint4*>(v);
  }
}

// ---------------- fused MLP: out = (relu(h@W1+b1)) @ W2 + b2 ---------------
// Block = 64 rows. Stage 1: 4 waves (2M x 2N), wave tile 32x128, H2 -> LDS.
// Stage 2: wave w handles rows w*16..w*16+15, K=256 from LDS, N=64.
__global__ __launch_bounds__(256) void k_mlp(const unsigned short* __restrict__ h,
                                             const unsigned short* __restrict__ B1p,
                                             const float* __restrict__ b1,
                                             const unsigned short* __restrict__ B2p,
                                             const float* __restrict__ b2,
                                             float* __restrict__ out) {
  __shared__ unsigned short hs[64][DHP + 8];  // +8 bf16 pad: stride 528 B
  const int tid = threadIdx.x;
  const int w = tid >> 6, l = tid & 63;
  const int wm = w >> 1, wn = w & 1;
  const int g = l >> 4, r16 = l & 15;
  const int m0 = blockIdx.x * 64 + wm * 32;

  f32x4 acc[2][8];
#pragma unroll
  for (int a = 0; a < 2; ++a)
#pragma unroll
    for (int b = 0; b < 8; ++b)
#pragma unroll
      for (int c = 0; c < 4; ++c) acc[a][b][c] = 0.f;

  int arow[2];
#pragma unroll
  for (int mr = 0; mr < 2; ++mr) {
    int rr = m0 + mr * 16 + r16;
    arow[mr] = rr < NN ? rr : NN - 1;
  }

  for (int s = 0; s < 4; ++s) {
    bf16x8 af[2];
#pragma unroll
    for (int mr = 0; mr < 2; ++mr) {
      const unsigned short* p = h + (size_t)arow[mr] * DIN + s * 32 + g * 4;
      s16x4 lo4 = *reinterpret_cast<const s16x4*>(p);
      s16x4 hi4 = *reinterpret_cast<const s16x4*>(p + 16);
#pragma unroll
      for (int j = 0; j < 4; ++j) { af[mr][j] = lo4[j]; af[mr][4 + j] = hi4[j]; }
    }
#pragma unroll
    for (int nr = 0; nr < 8; ++nr) {
      int t = wn * 8 + nr;
      bf16x8 bf = *reinterpret_cast<const bf16x8*>(B1p + (size_t)((t * 4 + s) * 64 + l) * 8);
      acc[0][nr] = __builtin_amdgcn_mfma_f32_16x16x32_bf16(af[0], bf, acc[0][nr], 0, 0, 0);
      acc[1][nr] = __builtin_amdgcn_mfma_f32_16x16x32_bf16(af[1], bf, acc[1][nr], 0, 0, 0);
    }
  }
  // bias + relu -> LDS (bf16)
#pragma unroll
  for (int mr = 0; mr < 2; ++mr)
#pragma unroll
    for (int nr = 0; nr < 8; ++nr) {
      int n = wn * 128 + nr * 16 + r16;
      float bias = (n < DH) ? b1[n] : 0.f;
#pragma unroll
      for (int i = 0; i < 4; ++i) {
        int rl = wm * 32 + mr * 16 + g * 4 + i;
        float v = acc[mr][nr][i] + bias;
        v = v > 0.f ? v : 0.f;
        if (n >= DH) v = 0.f;
        hs[rl][n] = f2bf(v);
      }
    }
  __syncthreads();

  // stage 2: rows w*16 .. w*16+15
  f32x4 acc2[4];
#pragma unroll
  for (int b = 0; b < 4; ++b)
#pragma unroll
    for (int c = 0; c < 4; ++c) acc2[b][c] = 0.f;

  for (int s = 0; s < 8; ++s) {
    const unsigned short* p = &hs[w * 16 + r16][s * 32 + g * 4];
    s16x4 lo4 = *reinterpret_cast<const s16x4*>(p);
    s16x4 hi4 = *reinterpret_cast<const s16x4*>(p + 16);
    bf16x8 af;
#pragma unroll
    for (int j = 0; j < 4; ++j) { af[j] = lo4[j]; af[4 + j] = hi4[j]; }
#pragma unroll
    for (int nr = 0; nr < 4; ++nr) {
      bf16x8 bf = *reinterpret_cast<const bf16x8*>(B2p + (size_t)((nr * 8 + s) * 64 + l) * 8);
      acc2[nr] = __builtin_amdgcn_mfma_f32_16x16x32_bf16(af, bf, acc2[nr], 0, 0, 0);
    }
  }
#pragma unroll
  for (int nr = 0; nr < 4; ++nr) {
    int n = nr * 16 + r16;
    float bias = b2[n];
#pragma unroll
    for (int i = 0; i < 4; ++i) {
      int grow = blockIdx.x * 64 + w * 16 + g * 4 + i;
      if (grow < NN) out[(size_t)grow * DO + n] = acc2[nr][i] + bias;
    }
  }
}

extern "C" void kernel_launch(void* const* d_in, const int* in_sizes, int n_in,
                              void* d_out, int out_size, void* d_ws, size_t ws_size,
                              hipStream_t stream) {
  const float* x = (const float*)d_in[0];
  const int* erow = (const int*)d_in[1];
  const int* ecol = (const int*)d_in[2];
  const float* eval_ = (const float*)d_in[3];
  const float* W1 = (const float*)d_in[4];
  const float* b1 = (const float*)d_in[5];
  const float* W2 = (const float*)d_in[6];
  const float* b2 = (const float*)d_in[7];
  float* out = (float*)d_out;

  char* ws = (char*)d_ws;
  size_t o = 0;
  uint* xb = (uint*)(ws + o);          o += (size_t)NN * 64 * 4;   // x bf16, 12.8 MB
  uint* hu = (uint*)(ws + o);          o += (size_t)NN * 64 * 4;   // h bf16, 12.8 MB
  unsigned short* B1p = (unsigned short*)(ws + o); o += 32768 * 2; // 64 KB
  unsigned short* B2p = (unsigned short*)(ws + o); o += 16384 * 2; // 32 KB
  o = (o + 255) & ~(size_t)255;
  int* off = (int*)(ws + o);           o += (256 << 10);
  int* cur = (int*)(ws + o);           o += (256 << 10);
  int* deg = (int*)(ws + o);           o += (256 << 10);
  int* bsum = (int*)(ws + o);          o += 4096;
  int* bbase = (int*)(ws + o);         o += 4096;
  uint* ep = (uint*)(ws + o);          // NE * 4 B = 3.2 MB

  const int NB = (NN + 255) / 256;  // 196

  k_cvt<<<3125, 256, 0, stream>>>(x, xb, deg);
  k_hist<<<(NE + 1023) / 1024, 256, 0, stream>>>(erow, deg);
  k_scanA<<<NB, 256, 0, stream>>>(deg, bsum);
  k_scanB<<<1, 256, 0, stream>>>(bsum, bbase, off, NB);
  k_scanC<<<NB, 256, 0, stream>>>(deg, bbase, off, cur);
  k_scatter<<<(NE + 1023) / 1024, 256, 0, stream>>>(erow, ecol, eval_, cur, ep);
  k_pack<<<24, 256, 0, stream>>>(W1, W2, B1p, B2p);
  k_spmm_csr<<<(NN + 3) / 4, 256, 0, stream>>>(xb, off, ep, hu);
  k_mlp<<<(NN + 63) / 64, 256, 0, stream>>>((const unsigned short*)hu, B1p, b1,
                                            B2p, b2, out);
}